// Round 2
// baseline (772.989 us; speedup 1.0000x reference)
//
#include <hip/hip_runtime.h>
#include <hip/hip_bf16.h>

// GCN layer: out = relu(D^-1/2 (A+I) D^-1/2 (x@W) + b)
// N=100000 nodes, E=1.6M edges, d_in=d_out=128, fp32.
//
// Pipeline:
//   K0 memset       : cnt = 0
//   K1 hist_kernel  : cnt[c] = #edges with col==c           (int atomics)
//   K2 scan_kernel  : offsets = exclusive_scan(cnt); cursor = offsets;
//                     dinv[i] = rsqrt(cnt[i]+1)             (self loop => deg>=1)
//   K3 scatter_kernel: CSR by destination: srcidx[cursor[c]++] = row
//   K4 gemm_kernel  : xw = x @ W       (fp32 VALU, W staged in LDS)
//   K5 accum_kernel : per node (1 wave): acc = dinv_i^2*xw[i]
//                     + sum_e dinv[r]*dinv_i*xw[r]; out = relu(acc + b)

__device__ __forceinline__ void fma4(float4& acc, float s, const float4& v) {
  acc.x = fmaf(s, v.x, acc.x);
  acc.y = fmaf(s, v.y, acc.y);
  acc.z = fmaf(s, v.z, acc.z);
  acc.w = fmaf(s, v.w, acc.w);
}

__global__ __launch_bounds__(256) void hist_kernel(const int* __restrict__ col,
                                                   int* __restrict__ cnt, int E) {
  int idx = blockIdx.x * blockDim.x + threadIdx.x;
  int stride = gridDim.x * blockDim.x;
  for (; idx < E; idx += stride) {
    atomicAdd(&cnt[col[idx]], 1);
  }
}

__global__ __launch_bounds__(1024) void scan_kernel(const int* __restrict__ cnt,
                                                    int* __restrict__ offsets,
                                                    int* __restrict__ cursor,
                                                    float* __restrict__ dinv, int N) {
  __shared__ int sums[1024];
  int tid = threadIdx.x;
  int per = (N + 1023) / 1024;
  int start = tid * per;
  int end = min(start + per, N);
  int s = 0;
  for (int i = start; i < end; ++i) s += cnt[i];
  sums[tid] = s;
  __syncthreads();
  // Hillis-Steele inclusive scan over the 1024 partial sums
  for (int off = 1; off < 1024; off <<= 1) {
    int t = (tid >= off) ? sums[tid - off] : 0;
    __syncthreads();
    sums[tid] += t;
    __syncthreads();
  }
  int run = sums[tid] - s;  // exclusive prefix of this thread's chunk
  for (int i = start; i < end; ++i) {
    int v = cnt[i];
    offsets[i] = run;
    cursor[i] = run;
    dinv[i] = rsqrtf((float)(v + 1));  // deg = in-degree + self loop >= 1
    run += v;
  }
}

__global__ __launch_bounds__(256) void scatter_kernel(const int* __restrict__ row,
                                                      const int* __restrict__ col,
                                                      int* __restrict__ cursor,
                                                      int* __restrict__ srcidx, int E) {
  int idx = blockIdx.x * blockDim.x + threadIdx.x;
  int stride = gridDim.x * blockDim.x;
  for (; idx < E; idx += stride) {
    int c = col[idx];
    int p = atomicAdd(&cursor[c], 1);
    srcidx[p] = row[idx];
  }
}

__global__ __launch_bounds__(256) void gemm_kernel(const float* __restrict__ x,
                                                   const float* __restrict__ W,
                                                   float* __restrict__ xw, int M) {
  __shared__ float Wl[128 * 128];  // 64 KiB
  __shared__ float xs[8][128];     // 4 KiB
  int tid = threadIdx.x;
  for (int i = tid * 4; i < 128 * 128; i += 256 * 4) {
    *(float4*)&Wl[i] = *(const float4*)&W[i];
  }
  int c4 = (tid & 31) * 4;  // 4-col group
  int rs = tid >> 5;        // row 0..7 within tile
  for (int base = blockIdx.x * 8; base < M; base += gridDim.x * 8) {
    int r = base + rs;
    float4 xv = make_float4(0.f, 0.f, 0.f, 0.f);
    if (r < M) xv = *(const float4*)&x[(size_t)r * 128 + c4];
    __syncthreads();  // also orders the W-load on first iteration
    *(float4*)&xs[rs][c4] = xv;
    __syncthreads();
    float4 acc = make_float4(0.f, 0.f, 0.f, 0.f);
#pragma unroll
    for (int k = 0; k < 128; k += 4) {
      float4 xk = *(float4*)&xs[rs][k];
      float4 w0 = *(float4*)&Wl[(k + 0) * 128 + c4];
      float4 w1 = *(float4*)&Wl[(k + 1) * 128 + c4];
      float4 w2 = *(float4*)&Wl[(k + 2) * 128 + c4];
      float4 w3 = *(float4*)&Wl[(k + 3) * 128 + c4];
      fma4(acc, xk.x, w0);
      fma4(acc, xk.y, w1);
      fma4(acc, xk.z, w2);
      fma4(acc, xk.w, w3);
    }
    if (r < M) *(float4*)&xw[(size_t)r * 128 + c4] = acc;
  }
}

__global__ __launch_bounds__(256) void accum_kernel(const float* __restrict__ xw,
                                                    const int* __restrict__ srcidx,
                                                    const int* __restrict__ offsets,
                                                    const int* __restrict__ cnt,
                                                    const float* __restrict__ dinv,
                                                    const float* __restrict__ bias,
                                                    float* __restrict__ out, int N) {
  int wave = (int)(blockIdx.x * (blockDim.x >> 6)) + (threadIdx.x >> 6);
  int lane = threadIdx.x & 63;
  if (wave >= N) return;
  int i = wave;
  float di = dinv[i];
  int off = offsets[i];
  int deg = cnt[i];

  // self-loop term: norm = dinv_i * dinv_i
  const float2* xws = (const float2*)(xw + (size_t)i * 128);
  float2 self = xws[lane];
  float sn = di * di;
  float2 acc;
  acc.x = self.x * sn;
  acc.y = self.y * sn;

  int j = 0;
  while (j < deg) {
    int batch = min(64, deg - j);
    int r = 0;
    float dv = 0.f;
    if (lane < batch) {
      r = srcidx[off + j + lane];
      dv = dinv[r];
    }
    for (int t = 0; t < batch; ++t) {
      int rs = __shfl(r, t);
      float norm = __shfl(dv, t) * di;
      const float2* xr = (const float2*)(xw + (size_t)rs * 128);
      float2 v = xr[lane];
      acc.x = fmaf(v.x, norm, acc.x);
      acc.y = fmaf(v.y, norm, acc.y);
    }
    j += batch;
  }

  float2 bb = ((const float2*)bias)[lane];
  acc.x = fmaxf(acc.x + bb.x, 0.f);
  acc.y = fmaxf(acc.y + bb.y, 0.f);
  ((float2*)(out + (size_t)i * 128))[lane] = acc;
}

extern "C" void kernel_launch(void* const* d_in, const int* in_sizes, int n_in,
                              void* d_out, int out_size, void* d_ws, size_t ws_size,
                              hipStream_t stream) {
  const float* x = (const float*)d_in[0];
  const int* edge = (const int*)d_in[1];
  const float* W = (const float*)d_in[2];
  const float* b = (const float*)d_in[3];
  float* out = (float*)d_out;

  int N = in_sizes[0] / 128;  // 100000
  int E = in_sizes[1] / 2;    // 1600000
  const int* row = edge;      // sources
  const int* col = edge + E;  // targets

  // workspace layout
  char* ws = (char*)d_ws;
  size_t off = 0;
  auto alloc = [&](size_t bytes) -> void* {
    off = (off + 255) & ~(size_t)255;
    void* p = ws + off;
    off += bytes;
    return p;
  };
  float* xw = (float*)alloc((size_t)N * 128 * sizeof(float));  // 51.2 MB
  int* cnt = (int*)alloc((size_t)N * sizeof(int));
  int* offs = (int*)alloc((size_t)N * sizeof(int));
  int* cursor = (int*)alloc((size_t)N * sizeof(int));
  float* dinv = (float*)alloc((size_t)N * sizeof(float));
  int* srcidx = (int*)alloc((size_t)E * sizeof(int));

  (void)hipMemsetAsync(cnt, 0, (size_t)N * sizeof(int), stream);
  hist_kernel<<<1024, 256, 0, stream>>>(col, cnt, E);
  scan_kernel<<<1, 1024, 0, stream>>>(cnt, offs, cursor, dinv, N);
  scatter_kernel<<<1024, 256, 0, stream>>>(row, col, cursor, srcidx, E);
  gemm_kernel<<<512, 256, 0, stream>>>(x, W, xw, N);

  int wavesPerBlock = 256 / 64;
  int nblocks = (N + wavesPerBlock - 1) / wavesPerBlock;
  accum_kernel<<<nblocks, 256, 0, stream>>>(xw, srcidx, offs, cnt, dinv, b, out, N);
}

// Round 4
// 483.507 us; speedup vs baseline: 1.5987x; 1.5987x over previous
//
#include <hip/hip_runtime.h>
#include <hip/hip_bf16.h>

// GCN layer: out = relu(D^-1/2 (A+I) D^-1/2 (x@W) + b)
// N=100000 nodes, E=1.6M edges, d_in=d_out=128, fp32.
//
// Pipeline:
//   K0 memset         : cnt = 0
//   K1 hist_kernel    : cnt[c] = in-degree                   (int atomics)
//   K2a reduce_chunks : partial[b] = sum(cnt[b*1024 .. +1023])
//   K2b scan_partials : partial = exclusive_scan(partial)    (1 block)
//   K2c scan_apply    : offsets/cursor = exclusive scan of cnt; dinv = rsqrt(deg+1)
//   K3 scatter_kernel : CSR by destination: srcidx[cursor[c]++] = row
//   K4 gemm_kernel    : xw = x @ W   (fp32 VALU, 8x8 register tile, swizzled LDS)
//   K5 accum_kernel   : per node (1 wave): acc = dinv_i^2*xw[i]
//                       + sum_e dinv[r]*dinv_i*xw[r]; out = relu(acc + b)

__device__ __forceinline__ void fma4(float4& acc, float s, const float4& v) {
  acc.x = fmaf(s, v.x, acc.x);
  acc.y = fmaf(s, v.y, acc.y);
  acc.z = fmaf(s, v.z, acc.z);
  acc.w = fmaf(s, v.w, acc.w);
}

__global__ __launch_bounds__(256) void hist_kernel(const int* __restrict__ col,
                                                   int* __restrict__ cnt, int E) {
  int idx = blockIdx.x * blockDim.x + threadIdx.x;
  int stride = gridDim.x * blockDim.x;
  for (; idx < E; idx += stride) {
    atomicAdd(&cnt[col[idx]], 1);
  }
}

// --- scan stage A: per-1024-chunk sums (coalesced int4) ---
__global__ __launch_bounds__(256) void reduce_chunks(const int* __restrict__ cnt,
                                                     int* __restrict__ partial, int N) {
  __shared__ int red[256];
  int base = blockIdx.x * 1024 + threadIdx.x * 4;
  int s = 0;
  if (base < N) {  // N % 4 == 0 so all 4 in range
    int4 v = *(const int4*)&cnt[base];
    s = v.x + v.y + v.z + v.w;
  }
  red[threadIdx.x] = s;
  __syncthreads();
  for (int off = 128; off > 0; off >>= 1) {
    if (threadIdx.x < off) red[threadIdx.x] += red[threadIdx.x + off];
    __syncthreads();
  }
  if (threadIdx.x == 0) partial[blockIdx.x] = red[0];
}

// --- scan stage B: exclusive scan of chunk sums (nchunks <= 256) ---
__global__ __launch_bounds__(256) void scan_partials(int* __restrict__ partial, int nchunks) {
  __shared__ int s[256];
  int tid = threadIdx.x;
  int v = (tid < nchunks) ? partial[tid] : 0;
  s[tid] = v;
  __syncthreads();
  for (int off = 1; off < 256; off <<= 1) {
    int t = (tid >= off) ? s[tid - off] : 0;
    __syncthreads();
    s[tid] += t;
    __syncthreads();
  }
  if (tid < nchunks) partial[tid] = s[tid] - v;  // exclusive
}

// --- scan stage C: in-chunk scan + write offsets/cursor/dinv ---
__global__ __launch_bounds__(256) void scan_apply(const int* __restrict__ cnt,
                                                  const int* __restrict__ partial,
                                                  int* __restrict__ offsets,
                                                  int* __restrict__ cursor,
                                                  float* __restrict__ dinv, int N) {
  __shared__ int s[256];
  int tid = threadIdx.x;
  int base = blockIdx.x * 1024 + tid * 4;
  int4 v = make_int4(0, 0, 0, 0);
  if (base < N) v = *(const int4*)&cnt[base];
  int sum = v.x + v.y + v.z + v.w;
  s[tid] = sum;
  __syncthreads();
  for (int off = 1; off < 256; off <<= 1) {
    int t = (tid >= off) ? s[tid - off] : 0;
    __syncthreads();
    s[tid] += t;
    __syncthreads();
  }
  if (base < N) {
    int e0 = s[tid] - sum + partial[blockIdx.x];
    int e1 = e0 + v.x;
    int e2 = e1 + v.y;
    int e3 = e2 + v.z;
    *(int4*)&offsets[base] = make_int4(e0, e1, e2, e3);
    *(int4*)&cursor[base] = make_int4(e0, e1, e2, e3);
    *(float4*)&dinv[base] =
        make_float4(rsqrtf((float)(v.x + 1)), rsqrtf((float)(v.y + 1)),
                    rsqrtf((float)(v.z + 1)), rsqrtf((float)(v.w + 1)));
  }
}

__global__ __launch_bounds__(256) void scatter_kernel(const int* __restrict__ row,
                                                      const int* __restrict__ col,
                                                      int* __restrict__ cursor,
                                                      int* __restrict__ srcidx, int E) {
  int idx = blockIdx.x * blockDim.x + threadIdx.x;
  int stride = gridDim.x * blockDim.x;
  for (; idx < E; idx += stride) {
    int c = col[idx];
    int p = atomicAdd(&cursor[c], 1);
    srcidx[p] = row[idx];
  }
}

// xw = x @ W. Block: 256 threads = 16 rowgroups x 16 colgroups; each thread
// computes 8 rows x 8 cols. Tile: 128 rows x 128 cols, K chunked by 32.
// xs stored unit-swizzled (16B unit u at u ^ ((r>>3)&7)) so the 8-apart-row
// float4 reads hit distinct banks.
__global__ __launch_bounds__(256) void gemm_kernel(const float* __restrict__ x,
                                                   const float* __restrict__ W,
                                                   float* __restrict__ xw, int M) {
  __shared__ float xs[128 * 32];  // 16 KiB, swizzled
  __shared__ float Wl[32 * 128];  // 16 KiB
  int tid = threadIdx.x;
  int rg = tid >> 4;  // 0..15
  int cg = tid & 15;  // 0..15
  int rowBase = blockIdx.x * 128;

  float4 acc0[8], acc1[8];
#pragma unroll
  for (int j = 0; j < 8; ++j) {
    acc0[j] = make_float4(0.f, 0.f, 0.f, 0.f);
    acc1[j] = make_float4(0.f, 0.f, 0.f, 0.f);
  }

  for (int kc = 0; kc < 4; ++kc) {
    // stage x chunk: rows rowBase..+127, k = kc*32..+31
#pragma unroll
    for (int m = 0; m < 4; ++m) {
      int l = tid + 256 * m;
      int r = l >> 3;       // 0..127
      int u = l & 7;        // 16B unit within 32-float row
      int gr = rowBase + r;
      float4 v = make_float4(0.f, 0.f, 0.f, 0.f);
      if (gr < M) v = *(const float4*)&x[(size_t)gr * 128 + kc * 32 + u * 4];
      int swz = u ^ ((r >> 3) & 7);
      *(float4*)&xs[r * 32 + swz * 4] = v;
    }
    // stage W chunk: k rows kc*32..+31, all 128 cols
#pragma unroll
    for (int m = 0; m < 4; ++m) {
      int l = tid + 256 * m;
      int k = l >> 5;   // 0..31
      int u = l & 31;   // float4 unit in 128-float row
      *(float4*)&Wl[k * 128 + u * 4] = *(const float4*)&W[(size_t)(kc * 32 + k) * 128 + u * 4];
    }
    __syncthreads();

#pragma unroll
    for (int k4 = 0; k4 < 32; k4 += 4) {
      float4 xa[8];
      int swz = (k4 >> 2) ^ (rg & 7);
#pragma unroll
      for (int j = 0; j < 8; ++j) {
        xa[j] = *(float4*)&xs[(rg * 8 + j) * 32 + swz * 4];
      }
#pragma unroll
      for (int kk = 0; kk < 4; ++kk) {
        float4 wb0 = *(float4*)&Wl[(k4 + kk) * 128 + cg * 8];
        float4 wb1 = *(float4*)&Wl[(k4 + kk) * 128 + cg * 8 + 4];
#pragma unroll
        for (int j = 0; j < 8; ++j) {
          float s = (kk == 0) ? xa[j].x : (kk == 1) ? xa[j].y : (kk == 2) ? xa[j].z : xa[j].w;
          fma4(acc0[j], s, wb0);
          fma4(acc1[j], s, wb1);
        }
      }
    }
    __syncthreads();
  }

#pragma unroll
  for (int j = 0; j < 8; ++j) {
    int gr = rowBase + rg * 8 + j;
    if (gr < M) {
      *(float4*)&xw[(size_t)gr * 128 + cg * 8] = acc0[j];
      *(float4*)&xw[(size_t)gr * 128 + cg * 8 + 4] = acc1[j];
    }
  }
}

__global__ __launch_bounds__(256) void accum_kernel(const float* __restrict__ xw,
                                                    const int* __restrict__ srcidx,
                                                    const int* __restrict__ offsets,
                                                    const int* __restrict__ cnt,
                                                    const float* __restrict__ dinv,
                                                    const float* __restrict__ bias,
                                                    float* __restrict__ out, int N) {
  int wave = (int)(blockIdx.x * (blockDim.x >> 6)) + (threadIdx.x >> 6);
  int lane = threadIdx.x & 63;
  if (wave >= N) return;
  int i = wave;
  float di = dinv[i];
  int off = offsets[i];
  int deg = cnt[i];

  // self-loop term: norm = dinv_i * dinv_i
  const float2* xws = (const float2*)(xw + (size_t)i * 128);
  float2 self = xws[lane];
  float sn = di * di;
  float2 acc;
  acc.x = self.x * sn;
  acc.y = self.y * sn;

  int j = 0;
  while (j < deg) {
    int batch = min(64, deg - j);
    int r = 0;
    float dv = 0.f;
    if (lane < batch) {
      r = srcidx[off + j + lane];
      dv = dinv[r];
    }
    for (int t = 0; t < batch; ++t) {
      int rs = __shfl(r, t);
      float norm = __shfl(dv, t) * di;
      const float2* xr = (const float2*)(xw + (size_t)rs * 128);
      float2 v = xr[lane];
      acc.x = fmaf(v.x, norm, acc.x);
      acc.y = fmaf(v.y, norm, acc.y);
    }
    j += batch;
  }

  float2 bb = ((const float2*)bias)[lane];
  acc.x = fmaxf(acc.x + bb.x, 0.f);
  acc.y = fmaxf(acc.y + bb.y, 0.f);
  ((float2*)(out + (size_t)i * 128))[lane] = acc;
}

extern "C" void kernel_launch(void* const* d_in, const int* in_sizes, int n_in,
                              void* d_out, int out_size, void* d_ws, size_t ws_size,
                              hipStream_t stream) {
  const float* x = (const float*)d_in[0];
  const int* edge = (const int*)d_in[1];
  const float* W = (const float*)d_in[2];
  const float* b = (const float*)d_in[3];
  float* out = (float*)d_out;

  int N = in_sizes[0] / 128;  // 100000
  int E = in_sizes[1] / 2;    // 1600000
  const int* row = edge;      // sources
  const int* col = edge + E;  // targets

  // workspace layout
  char* ws = (char*)d_ws;
  size_t off = 0;
  auto alloc = [&](size_t bytes) -> void* {
    off = (off + 255) & ~(size_t)255;
    void* p = ws + off;
    off += bytes;
    return p;
  };
  float* xw = (float*)alloc((size_t)N * 128 * sizeof(float));  // 51.2 MB
  int* cnt = (int*)alloc((size_t)N * sizeof(int));
  int* offs = (int*)alloc((size_t)N * sizeof(int));
  int* cursor = (int*)alloc((size_t)N * sizeof(int));
  float* dinv = (float*)alloc((size_t)N * sizeof(float));
  int* srcidx = (int*)alloc((size_t)E * sizeof(int));
  int* partial = (int*)alloc(256 * sizeof(int));

  int nchunks = (N + 1023) / 1024;  // 98 (must be <= 256)

  (void)hipMemsetAsync(cnt, 0, (size_t)N * sizeof(int), stream);
  hist_kernel<<<1024, 256, 0, stream>>>(col, cnt, E);
  reduce_chunks<<<nchunks, 256, 0, stream>>>(cnt, partial, N);
  scan_partials<<<1, 256, 0, stream>>>(partial, nchunks);
  scan_apply<<<nchunks, 256, 0, stream>>>(cnt, partial, offs, cursor, dinv, N);
  scatter_kernel<<<1024, 256, 0, stream>>>(row, col, cursor, srcidx, E);

  int gblocks = (N + 127) / 128;
  gemm_kernel<<<gblocks, 256, 0, stream>>>(x, W, xw, N);

  int wavesPerBlock = 256 / 64;
  int nblocks = (N + wavesPerBlock - 1) / wavesPerBlock;
  accum_kernel<<<nblocks, 256, 0, stream>>>(xw, srcidx, offs, cnt, dinv, b, out, N);
}